// Round 1
// baseline (216.161 us; speedup 1.0000x reference)
//
#include <hip/hip_runtime.h>

#define NL 100
#define BB 8
#define WW 1024
#define HH 1024
#define NPIX (WW * WW)
#define EPSF 1e-7f

// ws layout, 4-byte word offsets
#define OFF_CNT 0      // int  [800]
#define OFF_SX  800    // int  [800]
#define OFF_SY  1600   // int  [800]
#define OFF_XC  2400   // float[800]
#define OFF_YC  3200   // float[800]
#define OFF_MX  4000   // float-bits [800], nonneg
#define OFF_MY  4800   // float-bits [800]
#define OFF_INV 5600   // float[2]: inv_fg_den, inv_bg_den
#define WS_WORDS 5602

__global__ __launch_bounds__(256) void k_hist(const int* __restrict__ mask,
                                              int* __restrict__ ws) {
    __shared__ int s_cnt[4][NL];
    __shared__ int s_sx[4][NL];
    __shared__ int s_sy[4][NL];
    const int b  = blockIdx.y;
    const int wv = threadIdx.x >> 6;
    for (int i = threadIdx.x; i < 4 * NL; i += 256) {
        ((int*)s_cnt)[i] = 0; ((int*)s_sx)[i] = 0; ((int*)s_sy)[i] = 0;
    }
    __syncthreads();
    const int4* m4 = (const int4*)(mask + (size_t)b * NPIX);
    const int base4 = blockIdx.x * 1024;  // 1024 int4 = 4096 px / block
#pragma unroll
    for (int it = 0; it < 4; ++it) {
        const int i4 = base4 + it * 256 + threadIdx.x;
        const int4 mv = m4[i4];
        const int p  = i4 << 2;
        const int x0 = p & (HH - 1);   // H % 4 == 0, no wrap within the quad
        const int y  = p >> 10;
        atomicAdd(&s_cnt[wv][mv.x], 1); atomicAdd(&s_sx[wv][mv.x], x0);     atomicAdd(&s_sy[wv][mv.x], y);
        atomicAdd(&s_cnt[wv][mv.y], 1); atomicAdd(&s_sx[wv][mv.y], x0 + 1); atomicAdd(&s_sy[wv][mv.y], y);
        atomicAdd(&s_cnt[wv][mv.z], 1); atomicAdd(&s_sx[wv][mv.z], x0 + 2); atomicAdd(&s_sy[wv][mv.z], y);
        atomicAdd(&s_cnt[wv][mv.w], 1); atomicAdd(&s_sx[wv][mv.w], x0 + 3); atomicAdd(&s_sy[wv][mv.w], y);
    }
    __syncthreads();
    for (int i = threadIdx.x; i < NL; i += 256) {
        const int c = s_cnt[0][i] + s_cnt[1][i] + s_cnt[2][i] + s_cnt[3][i];
        if (c) {
            atomicAdd(&ws[OFF_CNT + b * NL + i], c);
            atomicAdd(&ws[OFF_SX  + b * NL + i], s_sx[0][i] + s_sx[1][i] + s_sx[2][i] + s_sx[3][i]);
            atomicAdd(&ws[OFF_SY  + b * NL + i], s_sy[0][i] + s_sy[1][i] + s_sy[2][i] + s_sy[3][i]);
        }
    }
}

__global__ void k_final(int* __restrict__ wsi) {
    float* wsf = (float*)wsi;
    const int t = threadIdx.x;
    if (t < BB * NL) {
        const int c = wsi[OFF_CNT + t];
        const float sc = (float)(c > 0 ? c : 1);
        wsf[OFF_XC + t] = (float)wsi[OFF_SX + t] / sc;
        wsf[OFF_YC + t] = (float)wsi[OFF_SY + t] / sc;
    }
    if (t == 0) {
        long long bg = 0;
        for (int b = 0; b < BB; ++b) bg += wsi[OFF_CNT + b * NL];
        const float n = (float)BB * (float)NPIX;
        const float fg_den = (float)((long long)BB * NPIX - bg) + EPSF * n;
        const float bg_den = (float)bg + EPSF * n;
        wsf[OFF_INV + 0] = 1.0f / fg_den;
        wsf[OFF_INV + 1] = 1.0f / bg_den;
    }
}

__global__ __launch_bounds__(256) void k_max(const int* __restrict__ mask,
                                             int* __restrict__ ws) {
    const float* wsf = (const float*)ws;
    __shared__ float s_xc[NL], s_yc[NL];
    __shared__ unsigned s_mx[4][NL], s_my[4][NL];
    const int b  = blockIdx.y;
    const int wv = threadIdx.x >> 6;
    for (int i = threadIdx.x; i < NL; i += 256) {
        s_xc[i] = wsf[OFF_XC + b * NL + i];
        s_yc[i] = wsf[OFF_YC + b * NL + i];
    }
    for (int i = threadIdx.x; i < 4 * NL; i += 256) {
        ((unsigned*)s_mx)[i] = 0u; ((unsigned*)s_my)[i] = 0u;
    }
    __syncthreads();
    const int4* m4 = (const int4*)(mask + (size_t)b * NPIX);
    const int base4 = blockIdx.x * 1024;
#pragma unroll
    for (int it = 0; it < 4; ++it) {
        const int i4 = base4 + it * 256 + threadIdx.x;
        const int4 mv = m4[i4];
        const int p  = i4 << 2;
        const float x0 = (float)(p & (HH - 1));
        const float y  = (float)(p >> 10);
        const int mm[4] = {mv.x, mv.y, mv.z, mv.w};
#pragma unroll
        for (int j = 0; j < 4; ++j) {
            const int m = mm[j];
            if (m != 0) {
                const float vx = x0 + (float)j - s_xc[m];
                const float vy = y - s_yc[m];
                if (vx > 0.0f) atomicMax(&s_mx[wv][m], __float_as_uint(vx));
                if (vy > 0.0f) atomicMax(&s_my[wv][m], __float_as_uint(vy));
            }
        }
    }
    __syncthreads();
    for (int i = threadIdx.x; i < NL; i += 256) {
        const unsigned ax = max(max(s_mx[0][i], s_mx[1][i]), max(s_mx[2][i], s_mx[3][i]));
        const unsigned ay = max(max(s_my[0][i], s_my[1][i]), max(s_my[2][i], s_my[3][i]));
        if (ax) atomicMax((unsigned*)&ws[OFF_MX + b * NL + i], ax);
        if (ay) atomicMax((unsigned*)&ws[OFF_MY + b * NL + i], ay);
    }
}

__global__ __launch_bounds__(256) void k_loss(const int* __restrict__ mask,
                                              const float* __restrict__ pred,
                                              const float* __restrict__ ig,
                                              const int* __restrict__ ws,
                                              float* __restrict__ out) {
    const float* wsf = (const float*)ws;
    __shared__ float s_xc[NL], s_yc[NL], s_imx[NL], s_imy[NL];
    const int b = blockIdx.y;
    for (int i = threadIdx.x; i < NL; i += 256) {
        s_xc[i] = wsf[OFF_XC + b * NL + i];
        s_yc[i] = wsf[OFF_YC + b * NL + i];
        const float mx = wsf[OFF_MX + b * NL + i];
        const float my = wsf[OFF_MY + b * NL + i];
        s_imx[i] = (mx == 0.0f) ? 1.0f : 1.0f / mx;
        s_imy[i] = (my == 0.0f) ? 1.0f : 1.0f / my;
    }
    __syncthreads();
    const float inv_fg = wsf[OFF_INV + 0];
    const float inv_bg = wsf[OFF_INV + 1];
    const int4*   m4  = (const int4*)(mask + (size_t)b * NPIX);
    const float4* ig4 = (const float4*)(ig + (size_t)b * NPIX);
    const float4* px4 = (const float4*)(pred + (size_t)(b * 2) * NPIX);
    const float4* py4 = (const float4*)(pred + (size_t)(b * 2 + 1) * NPIX);
    float* gx_out = out + 1 + (size_t)(b * 2) * NPIX;
    float* gy_out = out + 1 + (size_t)(b * 2 + 1) * NPIX;

    float acc = 0.0f;
    const int base4 = blockIdx.x * 1024;
#pragma unroll
    for (int it = 0; it < 4; ++it) {
        const int i4 = base4 + it * 256 + threadIdx.x;
        const int4   mv  = m4[i4];
        const float4 iv  = ig4[i4];
        const float4 pxv = px4[i4];
        const float4 pyv = py4[i4];
        const int p  = i4 << 2;
        const float x0 = (float)(p & (HH - 1));
        const float y  = (float)(p >> 10);
        const int*   mm  = (const int*)&mv;
        const float* igs = (const float*)&iv;
        const float* pxs = (const float*)&pxv;
        const float* pys = (const float*)&pyv;
#pragma unroll
        for (int j = 0; j < 4; ++j) {
            const int m = mm[j];
            float gx = 0.0f, gy = 0.0f, w;
            if (m != 0) {
                gx = (x0 + (float)j - s_xc[m]) * s_imx[m];
                gy = (y - s_yc[m]) * s_imy[m];
                w = inv_fg;
            } else {
                w = inv_bg;
            }
            w *= igs[j];
            const float dx = pxs[j] - gx;
            const float dy = pys[j] - gy;
            const float ax = fabsf(dx), ay = fabsf(dy);
            const float lx = (ax < 1.0f) ? 0.5f * dx * dx : ax - 0.5f;
            const float ly = (ay < 1.0f) ? 0.5f * dy * dy : ay - 0.5f;
            acc += (lx + ly) * w;
            gx_out[p + j] = gx;
            gy_out[p + j] = gy;
        }
    }
    // wave + block reduction
#pragma unroll
    for (int off = 32; off > 0; off >>= 1) acc += __shfl_down(acc, off, 64);
    __shared__ float s_part[4];
    const int lane = threadIdx.x & 63, wv = threadIdx.x >> 6;
    if (lane == 0) s_part[wv] = acc;
    __syncthreads();
    if (threadIdx.x == 0) atomicAdd(out, s_part[0] + s_part[1] + s_part[2] + s_part[3]);
}

extern "C" void kernel_launch(void* const* d_in, const int* in_sizes, int n_in,
                              void* d_out, int out_size, void* d_ws, size_t ws_size,
                              hipStream_t stream) {
    const float* pred = (const float*)d_in[0];
    const int*   mask = (const int*)d_in[1];
    const float* ig   = (const float*)d_in[2];
    float* out = (float*)d_out;
    int*   ws  = (int*)d_ws;

    hipMemsetAsync(d_ws, 0, WS_WORDS * sizeof(int), stream);
    hipMemsetAsync(d_out, 0, sizeof(float), stream);

    dim3 grid(256, BB);
    k_hist<<<grid, 256, 0, stream>>>(mask, ws);
    k_final<<<1, 800, 0, stream>>>(ws);
    k_max<<<grid, 256, 0, stream>>>(mask, ws);
    k_loss<<<grid, 256, 0, stream>>>(mask, pred, ig, ws, out);
}